// Round 1
// baseline (192.169 us; speedup 1.0000x reference)
//
#include <hip/hip_runtime.h>

#define OUT_H 512
#define OUT_W 512
#define BATCH 64
#define CHANS 3

__global__ __launch_bounds__(256) void st_bilinear_kernel(
    const float* __restrict__ U,      // [B, H, W, C]
    const float* __restrict__ theta,  // [B, 1]
    float* __restrict__ out)          // [B, H, W, C]
{
    int p = blockIdx.x * 256 + threadIdx.x;   // pixel index in [0, B*H*W)
    int j = p & (OUT_W - 1);                  // column
    int i = (p >> 9) & (OUT_H - 1);           // row
    int b = p >> 18;                          // batch

    float t = theta[b];
    float s, c;
    sincosf(t, &s, &c);

    const float scale = 2.0f / (float)(OUT_W - 1);  // H==W==512
    float gx = (float)j * scale - 1.0f;
    float gy = (float)i * scale - 1.0f;

    // rot = [[cos, -sin, 0],[sin, cos, 0]]
    float xs = c * gx - s * gy;
    float ys = s * gx + c * gy;

    float x = (xs + 1.0f) * ((float)(OUT_W - 1) * 0.5f);
    float y = (ys + 1.0f) * ((float)(OUT_H - 1) * 0.5f);

    float x0f = floorf(x);
    float y0f = floorf(y);
    int x0 = min(max((int)x0f,     0), OUT_W - 1);
    int x1 = min(max((int)x0f + 1, 0), OUT_W - 1);
    int y0 = min(max((int)y0f,     0), OUT_H - 1);
    int y1 = min(max((int)y0f + 1, 0), OUT_H - 1);

    float fx0 = (float)x0, fx1 = (float)x1;
    float fy0 = (float)y0, fy1 = (float)y1;

    float wa = (fx1 - x) * (fy1 - y);
    float wb = (fx1 - x) * (y - fy0);
    float wc = (x - fx0) * (fy1 - y);
    float wd = (x - fx0) * (y - fy0);

    const float* Ub = U + (size_t)b * (OUT_H * OUT_W * CHANS);
    const float* pa = Ub + ((size_t)y0 * OUT_W + x0) * CHANS;
    const float* pb = Ub + ((size_t)y1 * OUT_W + x0) * CHANS;
    const float* pc = Ub + ((size_t)y0 * OUT_W + x1) * CHANS;
    const float* pd = Ub + ((size_t)y1 * OUT_W + x1) * CHANS;

    float* po = out + (size_t)p * CHANS;
#pragma unroll
    for (int ch = 0; ch < CHANS; ++ch) {
        po[ch] = wa * pa[ch] + wb * pb[ch] + wc * pc[ch] + wd * pd[ch];
    }
}

extern "C" void kernel_launch(void* const* d_in, const int* in_sizes, int n_in,
                              void* d_out, int out_size, void* d_ws, size_t ws_size,
                              hipStream_t stream) {
    const float* U     = (const float*)d_in[0];
    const float* theta = (const float*)d_in[1];
    float* out = (float*)d_out;

    int total_pixels = BATCH * OUT_H * OUT_W;      // 16,777,216
    int blocks = total_pixels / 256;               // 65,536
    st_bilinear_kernel<<<blocks, 256, 0, stream>>>(U, theta, out);
}